// Round 20
// baseline (478.023 us; speedup 1.0000x reference)
//
#include <hip/hip_runtime.h>
#include <cstdint>
#include <cstddef>

#define DI __device__ __forceinline__

namespace {

constexpr int B_ = 2, S_ = 1024, H_ = 1024, NH_ = 16, FF_ = 4096, E_ = 8;
constexpr int T_ = B_ * S_;                     // 2048 tokens
constexpr int MAXTILES = (T_ * 2) / 128 + E_;   // 40 row-tiles (128 slots each)
constexpr int PADSLOTS = MAXTILES * 128;        // 5120 slots
constexpr size_t APL = (size_t)T_ * H_;         // activation plane offset
constexpr size_t WPL = (size_t)H_ * H_;         // weight plane offset

typedef __attribute__((ext_vector_type(8))) short short8;
typedef __attribute__((ext_vector_type(4))) float f32x4;

DI float bf2f(unsigned short u) { return __uint_as_float(((unsigned)u) << 16); }
DI unsigned short f2bf(float f) {
  unsigned u = __float_as_uint(f);
  u += 0x7fffu + ((u >> 16) & 1u);
  return (unsigned short)(u >> 16);
}
// convert 8 floats (two float4) -> 8 bf16
DI void cvt8(const float4 a, const float4 b, unsigned short* d) {
  d[0] = f2bf(a.x); d[1] = f2bf(a.y); d[2] = f2bf(a.z); d[3] = f2bf(a.w);
  d[4] = f2bf(b.x); d[5] = f2bf(b.y); d[6] = f2bf(b.z); d[7] = f2bf(b.w);
}

// ---------------------------------------------------------------- RMSNorm
// MODE 1: fp32 out + single bf16 outb.   MODE 2: hi/lo split planes in outb.
template <int MODE>
__global__ __launch_bounds__(256) void rmsnorm_kernel(const float* __restrict__ in,
                                                      const float* __restrict__ w,
                                                      float* __restrict__ out,
                                                      unsigned short* __restrict__ outb) {
  const int t = blockIdx.x, tid = threadIdx.x;
  const float4* row = (const float4*)(in + (size_t)t * H_);
  float4 v = row[tid];
  float ss = v.x * v.x + v.y * v.y + v.z * v.z + v.w * v.w;
  #pragma unroll
  for (int off = 32; off; off >>= 1) ss += __shfl_down(ss, off);
  __shared__ float red[4];
  if ((tid & 63) == 0) red[tid >> 6] = ss;
  __syncthreads();
  const float total = red[0] + red[1] + red[2] + red[3];
  const float rinv = 1.f / sqrtf(total * (1.f / (float)H_) + 1e-6f);
  const float4 wv = ((const float4*)w)[tid];
  float o[4];
  o[0] = v.x * rinv * wv.x; o[1] = v.y * rinv * wv.y;
  o[2] = v.z * rinv * wv.z; o[3] = v.w * rinv * wv.w;
  if (MODE == 1) {
    float4 o4 = {o[0], o[1], o[2], o[3]};
    ((float4*)(out + (size_t)t * H_))[tid] = o4;
    unsigned short* p = outb + (size_t)t * H_ + tid * 4;
    p[0] = f2bf(o[0]); p[1] = f2bf(o[1]); p[2] = f2bf(o[2]); p[3] = f2bf(o[3]);
  } else {
    __align__(8) unsigned short hi[4], lo[4];
    #pragma unroll
    for (int j = 0; j < 4; j++) {
      hi[j] = f2bf(o[j]);
      lo[j] = f2bf(o[j] - bf2f(hi[j]));
    }
    const size_t idx = (size_t)t * H_ + tid * 4;
    *(uint2*)&outb[idx] = *(const uint2*)hi;
    *(uint2*)&outb[APL + idx] = *(const uint2*)lo;
  }
}

// ---------------------------------------- fp32 weight -> hi/lo bf16 planes
__global__ __launch_bounds__(256) void cvt_wsplit(const float* __restrict__ src,
                                                  unsigned short* __restrict__ dst, int n8) {
  const int i = blockIdx.x * 256 + threadIdx.x;
  if (i < n8) {
    const float4 a = ((const float4*)src)[2 * i];
    const float4 b = ((const float4*)src)[2 * i + 1];
    const float xs[8] = {a.x, a.y, a.z, a.w, b.x, b.y, b.z, b.w};
    __align__(16) unsigned short hi[8], lo[8];
    #pragma unroll
    for (int j = 0; j < 8; j++) {
      hi[j] = f2bf(xs[j]);
      lo[j] = f2bf(xs[j] - bf2f(hi[j]));
    }
    ((uint4*)dst)[i] = *(const uint4*)hi;
    ((uint4*)(dst + WPL))[i] = *(const uint4*)lo;
  }
}

// ---------------------------------------------------- fp32 -> bf16 convert
__global__ __launch_bounds__(256) void cvt_ws(const float* __restrict__ src,
                                              unsigned short* __restrict__ dst, int n8) {
  const int i = blockIdx.x * 256 + threadIdx.x;
  if (i < n8) {
    const float4 a = ((const float4*)src)[2 * i];
    const float4 b = ((const float4*)src)[2 * i + 1];
    __align__(16) unsigned short t[8];
    cvt8(a, b, t);
    ((uint4*)dst)[i] = *(const uint4*)t;
  }
}

// ------------------------- planar split-bf16 MFMA NT GEMM (pure bf16 staging)
template <int EPI>
__global__ __launch_bounds__(256, 3) void gemm_split(const unsigned short* __restrict__ As,
                                                     const unsigned short* __restrict__ Wsa,
                                                     const unsigned short* __restrict__ Wsb,
                                                     const unsigned short* __restrict__ Wsc,
                                                     float* __restrict__ Ca,
                                                     float* __restrict__ Cb,
                                                     float* __restrict__ Cc,
                                                     const float* __restrict__ resid) {
  constexpr int K = 1024;
  constexpr int LDA = 40;
  __shared__ __align__(16) unsigned short sAh[128 * LDA];
  __shared__ __align__(16) unsigned short sAl[128 * LDA];
  __shared__ __align__(16) unsigned short sWh[128 * LDA];
  __shared__ __align__(16) unsigned short sWl[128 * LDA];
  const int tid = threadIdx.x;
  const int m0 = blockIdx.x << 7, n0 = blockIdx.y << 7;
  const unsigned short* W = Wsa; float* C = Ca;
  if (EPI == 0) {
    if (blockIdx.z == 1) { W = Wsb; C = Cb; }
    else if (blockIdx.z == 2) { W = Wsc; C = Cc; }
  }
  const int wave = tid >> 6, lane = tid & 63, wm = wave >> 1, wn = wave & 1;
  const int g16 = lane >> 4, l15 = lane & 15;
  const int row = tid >> 1, kq = (tid & 1) << 4;
  const unsigned short* pah = As + (size_t)(m0 + row) * K + kq;
  const unsigned short* pal = pah + APL;
  const unsigned short* pwh = W + (size_t)(n0 + row) * K + kq;
  const unsigned short* pwl = pwh + WPL;
  f32x4 acc[4][4];
  #pragma unroll
  for (int m = 0; m < 4; m++)
    #pragma unroll
    for (int n = 0; n < 4; n++) acc[m][n] = (f32x4){0.f, 0.f, 0.f, 0.f};

  uint4 rah0 = *(const uint4*)pah, rah1 = *(const uint4*)(pah + 8);
  uint4 ral0 = *(const uint4*)pal, ral1 = *(const uint4*)(pal + 8);
  uint4 rwh0 = *(const uint4*)pwh, rwh1 = *(const uint4*)(pwh + 8);
  uint4 rwl0 = *(const uint4*)pwl, rwl1 = *(const uint4*)(pwl + 8);

  for (int k0 = 0; k0 < K; k0 += 32) {
    __syncthreads();
    *(uint4*)&sAh[row * LDA + kq] = rah0;
    *(uint4*)&sAh[row * LDA + kq + 8] = rah1;
    *(uint4*)&sAl[row * LDA + kq] = ral0;
    *(uint4*)&sAl[row * LDA + kq + 8] = ral1;
    *(uint4*)&sWh[row * LDA + kq] = rwh0;
    *(uint4*)&sWh[row * LDA + kq + 8] = rwh1;
    *(uint4*)&sWl[row * LDA + kq] = rwl0;
    *(uint4*)&sWl[row * LDA + kq + 8] = rwl1;
    // prefetch next phase BEFORE barrier2: loads in flight across barrier + MFMA
    if (k0 + 32 < K) {
      rah0 = *(const uint4*)(pah + k0 + 32); rah1 = *(const uint4*)(pah + k0 + 40);
      ral0 = *(const uint4*)(pal + k0 + 32); ral1 = *(const uint4*)(pal + k0 + 40);
      rwh0 = *(const uint4*)(pwh + k0 + 32); rwh1 = *(const uint4*)(pwh + k0 + 40);
      rwl0 = *(const uint4*)(pwl + k0 + 32); rwl1 = *(const uint4*)(pwl + k0 + 40);
    }
    __syncthreads();
    short8 ah[4], al[4], wh[4], wl[4];
    #pragma unroll
    for (int m = 0; m < 4; m++) {
      ah[m] = *(const short8*)&sAh[(wm * 64 + m * 16 + l15) * LDA + g16 * 8];
      al[m] = *(const short8*)&sAl[(wm * 64 + m * 16 + l15) * LDA + g16 * 8];
    }
    #pragma unroll
    for (int n = 0; n < 4; n++) {
      wh[n] = *(const short8*)&sWh[(wn * 64 + n * 16 + l15) * LDA + g16 * 8];
      wl[n] = *(const short8*)&sWl[(wn * 64 + n * 16 + l15) * LDA + g16 * 8];
    }
    #pragma unroll
    for (int m = 0; m < 4; m++)
      #pragma unroll
      for (int n = 0; n < 4; n++) {
        acc[m][n] = __builtin_amdgcn_mfma_f32_16x16x32_bf16(ah[m], wh[n], acc[m][n], 0, 0, 0);
        acc[m][n] = __builtin_amdgcn_mfma_f32_16x16x32_bf16(al[m], wh[n], acc[m][n], 0, 0, 0);
        acc[m][n] = __builtin_amdgcn_mfma_f32_16x16x32_bf16(ah[m], wl[n], acc[m][n], 0, 0, 0);
      }
  }
  #pragma unroll
  for (int m = 0; m < 4; m++)
    #pragma unroll
    for (int r = 0; r < 4; r++) {
      const int grow = m0 + wm * 64 + m * 16 + g16 * 4 + r;
      #pragma unroll
      for (int n = 0; n < 4; n++) {
        const int gcol = n0 + wn * 64 + n * 16 + l15;
        float v = acc[m][n][r];
        if (EPI == 1) v += resid[(size_t)grow * 1024 + gcol];
        C[(size_t)grow * 1024 + gcol] = v;
      }
    }
}

// ---------------------------------------------------------------- RoPE (fp32, [t][h*64+d])
__global__ __launch_bounds__(256) void rope_kernel(float* __restrict__ buf) {
  const int id = blockIdx.x * 256 + threadIdx.x;  // T_*NH_*32 total
  const int t = id >> 9;
  const int rem = id & 511;
  const int h = rem >> 5, j = rem & 31;
  const int s = t & (S_ - 1);
  const float inv = exp2f(-(float)j * (0.41524101186092029f));
  const float ang = (float)s * inv;
  const float c = cosf(ang), sn = sinf(ang);
  float* p = buf + (size_t)t * H_ + h * 64;
  const float xa = p[j], xb = p[j + 32];
  p[j] = xa * c - xb * sn;
  p[j + 32] = xb * c + xa * sn;
}

// ------------------------------------------------- flash attention, split-bf16 MFMA
__global__ __launch_bounds__(512, 2) void attn_mfma(const float* __restrict__ q,
                                                    const float* __restrict__ k,
                                                    const float* __restrict__ v,
                                                    unsigned short* __restrict__ aos) {
  constexpr int LDW = 136;  // ushort stride (128 + 8 pad)
  __shared__ __align__(16) unsigned short sP[128 * LDW];   // Q staging, then P
  __shared__ __align__(16) unsigned short sK[64 * LDW];
  __shared__ __align__(16) unsigned short sVt[64 * LDW];
  const int tid = threadIdx.x;
  const int bh = blockIdx.x >> 3, chunk = blockIdx.x & 7;
  const int b = bh >> 4, h = bh & (NH_ - 1);
  const int w = tid >> 6, lane = tid & 63, g = lane >> 4, l15 = lane & 15;

  {
    const int row = tid >> 2, d0 = (tid & 3) << 4;
    const float* qp = q + ((size_t)((b << 10) + (chunk << 7) + row)) * H_ + h * 64 + d0;
    __align__(16) unsigned short thi[16], tlo[16];
    #pragma unroll
    for (int c = 0; c < 4; c++) {
      const float4 x = ((const float4*)qp)[c];
      const float xs[4] = {x.x, x.y, x.z, x.w};
      #pragma unroll
      for (int j = 0; j < 4; j++) {
        const float val = xs[j] * 0.125f;
        const unsigned short hi = f2bf(val);
        thi[c * 4 + j] = hi;
        tlo[c * 4 + j] = f2bf(val - bf2f(hi));
      }
    }
    uint4* dh = (uint4*)&sP[row * LDW + d0];
    dh[0] = ((const uint4*)thi)[0]; dh[1] = ((const uint4*)thi)[1];
    uint4* dl = (uint4*)&sP[row * LDW + 64 + d0];
    dl[0] = ((const uint4*)tlo)[0]; dl[1] = ((const uint4*)tlo)[1];
  }
  __syncthreads();
  short8 aqh[2], aql[2];
  #pragma unroll
  for (int s2 = 0; s2 < 2; s2++) {
    aqh[s2] = *(const short8*)&sP[(w * 16 + l15) * LDW + s2 * 32 + g * 8];
    aql[s2] = *(const short8*)&sP[(w * 16 + l15) * LDW + 64 + s2 * 32 + g * 8];
  }
  __syncthreads();

  f32x4 accO[4];
  #pragma unroll
  for (int n = 0; n < 4; n++) accO[n] = (f32x4){0.f, 0.f, 0.f, 0.f};
  float mrun[4] = {-3.0e38f, -3.0e38f, -3.0e38f, -3.0e38f};
  float lrun[4] = {0.f, 0.f, 0.f, 0.f};

  const int krow = tid >> 3, dk0 = (tid & 7) << 3;
  const int vd = tid >> 3, vk0 = (tid & 7) << 3;
  const float* kp0 = k + ((size_t)((b << 10) + krow)) * H_ + h * 64 + dk0;
  const float* vp0 = v + ((size_t)(b << 10)) * H_ + h * 64 + vd;

  float krg[8], vrg[8];
  {
    const float4 a = *(const float4*)kp0;
    const float4 c = *(const float4*)(kp0 + 4);
    krg[0] = a.x; krg[1] = a.y; krg[2] = a.z; krg[3] = a.w;
    krg[4] = c.x; krg[5] = c.y; krg[6] = c.z; krg[7] = c.w;
    #pragma unroll
    for (int i = 0; i < 8; i++) vrg[i] = vp0[(size_t)(vk0 + i) * H_];
  }
  {
    __align__(16) unsigned short thi[8], tlo[8];
    #pragma unroll
    for (int j = 0; j < 8; j++) {
      const unsigned short hi = f2bf(krg[j]);
      thi[j] = hi; tlo[j] = f2bf(krg[j] - bf2f(hi));
    }
    *(uint4*)&sK[krow * LDW + dk0] = *(const uint4*)thi;
    *(uint4*)&sK[krow * LDW + 64 + dk0] = *(const uint4*)tlo;
    #pragma unroll
    for (int j = 0; j < 8; j++) {
      const unsigned short hi = f2bf(vrg[j]);
      thi[j] = hi; tlo[j] = f2bf(vrg[j] - bf2f(hi));
    }
    *(uint4*)&sVt[vd * LDW + vk0] = *(const uint4*)thi;
    *(uint4*)&sVt[vd * LDW + 64 + vk0] = *(const uint4*)tlo;
  }
  __syncthreads();

  for (int kt = 0; kt < S_ / 64; kt++) {
    if (kt < S_ / 64 - 1) {
      const float* kp = kp0 + (size_t)((kt + 1) * 64) * H_;
      const float4 a = *(const float4*)kp;
      const float4 c = *(const float4*)(kp + 4);
      krg[0] = a.x; krg[1] = a.y; krg[2] = a.z; krg[3] = a.w;
      krg[4] = c.x; krg[5] = c.y; krg[6] = c.z; krg[7] = c.w;
      #pragma unroll
      for (int i = 0; i < 8; i++) vrg[i] = vp0[(size_t)((kt + 1) * 64 + vk0 + i) * H_];
    }
    f32x4 accS[4];
    #pragma unroll
    for (int n = 0; n < 4; n++) accS[n] = (f32x4){0.f, 0.f, 0.f, 0.f};
    #pragma unroll
    for (int s2 = 0; s2 < 2; s2++) {
      #pragma unroll
      for (int n = 0; n < 4; n++) {
        const short8 bkh = *(const short8*)&sK[(n * 16 + l15) * LDW + s2 * 32 + g * 8];
        const short8 bkl = *(const short8*)&sK[(n * 16 + l15) * LDW + 64 + s2 * 32 + g * 8];
        accS[n] = __builtin_amdgcn_mfma_f32_16x16x32_bf16(aqh[s2], bkh, accS[n], 0, 0, 0);
        accS[n] = __builtin_amdgcn_mfma_f32_16x16x32_bf16(aql[s2], bkh, accS[n], 0, 0, 0);
        accS[n] = __builtin_amdgcn_mfma_f32_16x16x32_bf16(aqh[s2], bkl, accS[n], 0, 0, 0);
      }
    }
    float corr[4];
    float pv_[4][4];
    #pragma unroll
    for (int r = 0; r < 4; r++) {
      float tm = fmaxf(fmaxf(accS[0][r], accS[1][r]), fmaxf(accS[2][r], accS[3][r]));
      tm = fmaxf(tm, __shfl_xor(tm, 1));
      tm = fmaxf(tm, __shfl_xor(tm, 2));
      tm = fmaxf(tm, __shfl_xor(tm, 4));
      tm = fmaxf(tm, __shfl_xor(tm, 8));
      const float mnew = fmaxf(mrun[r], tm);
      corr[r] = __expf(mrun[r] - mnew);
      mrun[r] = mnew;
      float ssum = 0.f;
      #pragma unroll
      for (int n = 0; n < 4; n++) {
        const float p = __expf(accS[n][r] - mnew);
        pv_[n][r] = p; ssum += p;
      }
      ssum += __shfl_xor(ssum, 1);
      ssum += __shfl_xor(ssum, 2);
      ssum += __shfl_xor(ssum, 4);
      ssum += __shfl_xor(ssum, 8);
      lrun[r] = lrun[r] * corr[r] + ssum;
    }
    #pragma unroll
    for (int n = 0; n < 4; n++)
      #pragma unroll
      for (int r = 0; r < 4; r++) accO[n][r] *= corr[r];
    #pragma unroll
    for (int n = 0; n < 4; n++)
      #pragma unroll
      for (int r = 0; r < 4; r++) {
        const float p = pv_[n][r];
        const unsigned short hi = f2bf(p);
        unsigned short* pp = &sP[(w * 16 + g * 4 + r) * LDW + (n * 16 + l15)];
        pp[0] = hi;
        pp[64] = f2bf(p - bf2f(hi));
      }
    #pragma unroll
    for (int s2 = 0; s2 < 2; s2++) {
      const short8 aph = *(const short8*)&sP[(w * 16 + l15) * LDW + s2 * 32 + g * 8];
      const short8 apl = *(const short8*)&sP[(w * 16 + l15) * LDW + 64 + s2 * 32 + g * 8];
      #pragma unroll
      for (int n = 0; n < 4; n++) {
        const short8 bvh = *(const short8*)&sVt[(n * 16 + l15) * LDW + s2 * 32 + g * 8];
        const short8 bvl = *(const short8*)&sVt[(n * 16 + l15) * LDW + 64 + s2 * 32 + g * 8];
        accO[n] = __builtin_amdgcn_mfma_f32_16x16x32_bf16(aph, bvh, accO[n], 0, 0, 0);
        accO[n] = __builtin_amdgcn_mfma_f32_16x16x32_bf16(apl, bvh, accO[n], 0, 0, 0);
        accO[n] = __builtin_amdgcn_mfma_f32_16x16x32_bf16(aph, bvl, accO[n], 0, 0, 0);
      }
    }
    __syncthreads();
    if (kt < S_ / 64 - 1) {
      __align__(16) unsigned short thi[8], tlo[8];
      #pragma unroll
      for (int j = 0; j < 8; j++) {
        const unsigned short hi = f2bf(krg[j]);
        thi[j] = hi; tlo[j] = f2bf(krg[j] - bf2f(hi));
      }
      *(uint4*)&sK[krow * LDW + dk0] = *(const uint4*)thi;
      *(uint4*)&sK[krow * LDW + 64 + dk0] = *(const uint4*)tlo;
      #pragma unroll
      for (int j = 0; j < 8; j++) {
        const unsigned short hi = f2bf(vrg[j]);
        thi[j] = hi; tlo[j] = f2bf(vrg[j] - bf2f(hi));
      }
      *(uint4*)&sVt[vd * LDW + vk0] = *(const uint4*)thi;
      *(uint4*)&sVt[vd * LDW + 64 + vk0] = *(const uint4*)tlo;
    }
    __syncthreads();
  }
  float inv[4];
  #pragma unroll
  for (int r = 0; r < 4; r++) inv[r] = 1.f / lrun[r];
  unsigned short* aoh = aos + ((size_t)((b << 10) + (chunk << 7) + w * 16)) * H_ + h * 64;
  #pragma unroll
  for (int n = 0; n < 4; n++)
    #pragma unroll
    for (int r = 0; r < 4; r++) {
      const float val = accO[n][r] * inv[r];
      const unsigned short hi = f2bf(val);
      const size_t idx = (size_t)(g * 4 + r) * H_ + n * 16 + l15;
      aoh[idx] = hi;
      aoh[APL + idx] = f2bf(val - bf2f(hi));
    }
}

// ------------------------- Wo GEMM: planar A (aos), planar W, fp32 out + resid
__global__ __launch_bounds__(256, 3) void gemm_wo(const unsigned short* __restrict__ As,
                                                  const unsigned short* __restrict__ Ws,
                                                  float* __restrict__ C,
                                                  const float* __restrict__ resid) {
  constexpr int K = 1024;
  constexpr int LDA = 40;
  __shared__ __align__(16) unsigned short sAh[128 * LDA];
  __shared__ __align__(16) unsigned short sAl[128 * LDA];
  __shared__ __align__(16) unsigned short sWh[128 * LDA];
  __shared__ __align__(16) unsigned short sWl[128 * LDA];
  const int tid = threadIdx.x;
  const int m0 = blockIdx.x << 7, n0 = blockIdx.y << 7;
  const int wave = tid >> 6, lane = tid & 63, wm = wave >> 1, wn = wave & 1;
  const int g16 = lane >> 4, l15 = lane & 15;
  const int row = tid >> 1, kq = (tid & 1) << 4;
  const unsigned short* pah = As + (size_t)(m0 + row) * K + kq;
  const unsigned short* pal = pah + APL;
  const unsigned short* pwh = Ws + (size_t)(n0 + row) * K + kq;
  const unsigned short* pwl = pwh + WPL;
  f32x4 acc[4][4];
  #pragma unroll
  for (int m = 0; m < 4; m++)
    #pragma unroll
    for (int n = 0; n < 4; n++) acc[m][n] = (f32x4){0.f, 0.f, 0.f, 0.f};

  uint4 rah0 = *(const uint4*)pah, rah1 = *(const uint4*)(pah + 8);
  uint4 ral0 = *(const uint4*)pal, ral1 = *(const uint4*)(pal + 8);
  uint4 rwh0 = *(const uint4*)pwh, rwh1 = *(const uint4*)(pwh + 8);
  uint4 rwl0 = *(const uint4*)pwl, rwl1 = *(const uint4*)(pwl + 8);

  for (int k0 = 0; k0 < K; k0 += 32) {
    __syncthreads();
    *(uint4*)&sAh[row * LDA + kq] = rah0;
    *(uint4*)&sAh[row * LDA + kq + 8] = rah1;
    *(uint4*)&sAl[row * LDA + kq] = ral0;
    *(uint4*)&sAl[row * LDA + kq + 8] = ral1;
    *(uint4*)&sWh[row * LDA + kq] = rwh0;
    *(uint4*)&sWh[row * LDA + kq + 8] = rwh1;
    *(uint4*)&sWl[row * LDA + kq] = rwl0;
    *(uint4*)&sWl[row * LDA + kq + 8] = rwl1;
    if (k0 + 32 < K) {
      rah0 = *(const uint4*)(pah + k0 + 32); rah1 = *(const uint4*)(pah + k0 + 40);
      ral0 = *(const uint4*)(pal + k0 + 32); ral1 = *(const uint4*)(pal + k0 + 40);
      rwh0 = *(const uint4*)(pwh + k0 + 32); rwh1 = *(const uint4*)(pwh + k0 + 40);
      rwl0 = *(const uint4*)(pwl + k0 + 32); rwl1 = *(const uint4*)(pwl + k0 + 40);
    }
    __syncthreads();
    short8 ah[4], al[4], wh[4], wl[4];
    #pragma unroll
    for (int m = 0; m < 4; m++) {
      ah[m] = *(const short8*)&sAh[(wm * 64 + m * 16 + l15) * LDA + g16 * 8];
      al[m] = *(const short8*)&sAl[(wm * 64 + m * 16 + l15) * LDA + g16 * 8];
    }
    #pragma unroll
    for (int n = 0; n < 4; n++) {
      wh[n] = *(const short8*)&sWh[(wn * 64 + n * 16 + l15) * LDA + g16 * 8];
      wl[n] = *(const short8*)&sWl[(wn * 64 + n * 16 + l15) * LDA + g16 * 8];
    }
    #pragma unroll
    for (int m = 0; m < 4; m++)
      #pragma unroll
      for (int n = 0; n < 4; n++) {
        acc[m][n] = __builtin_amdgcn_mfma_f32_16x16x32_bf16(ah[m], wh[n], acc[m][n], 0, 0, 0);
        acc[m][n] = __builtin_amdgcn_mfma_f32_16x16x32_bf16(al[m], wh[n], acc[m][n], 0, 0, 0);
        acc[m][n] = __builtin_amdgcn_mfma_f32_16x16x32_bf16(ah[m], wl[n], acc[m][n], 0, 0, 0);
      }
  }
  #pragma unroll
  for (int m = 0; m < 4; m++)
    #pragma unroll
    for (int r = 0; r < 4; r++) {
      const int grow = m0 + wm * 64 + m * 16 + g16 * 4 + r;
      #pragma unroll
      for (int n = 0; n < 4; n++) {
        const int gcol = n0 + wn * 64 + n * 16 + l15;
        C[(size_t)grow * 1024 + gcol] = acc[m][n][r] + resid[(size_t)grow * 1024 + gcol];
      }
    }
}

// ---------------------------------------------------------------- router
__global__ __launch_bounds__(256) void router_kernel(const float* __restrict__ x2,
                                                     const float* __restrict__ Wr,
                                                     float* __restrict__ probs,
                                                     int* __restrict__ texp,
                                                     float* __restrict__ tw) {
  const int wid = threadIdx.x >> 6, lane = threadIdx.x & 63;
  const int t = (blockIdx.x << 2) + wid;
  const float* xr = x2 + (size_t)t * H_;
  float4 xv[4];
  #pragma unroll
  for (int i = 0; i < 4; i++) xv[i] = *(const float4*)&xr[(i << 8) + (lane << 2)];
  float acc[E_];
  #pragma unroll
  for (int e = 0; e < E_; e++) acc[e] = 0.f;
  #pragma unroll
  for (int i = 0; i < 4; i++) {
    #pragma unroll
    for (int e = 0; e < E_; e++) {
      const float4 wv = *(const float4*)&Wr[e * H_ + (i << 8) + (lane << 2)];
      acc[e] += xv[i].x * wv.x + xv[i].y * wv.y + xv[i].z * wv.z + xv[i].w * wv.w;
    }
  }
  #pragma unroll
  for (int e = 0; e < E_; e++) {
    #pragma unroll
    for (int off = 32; off; off >>= 1) acc[e] += __shfl_xor(acc[e], off);
  }
  if (lane == 0) {
    float mx = acc[0];
    #pragma unroll
    for (int e = 1; e < E_; e++) mx = fmaxf(mx, acc[e]);
    float pp[E_]; float sum = 0.f;
    #pragma unroll
    for (int e = 0; e < E_; e++) { pp[e] = __expf(acc[e] - mx); sum += pp[e]; }
    const float isum = 1.f / sum;
    #pragma unroll
    for (int e = 0; e < E_; e++) pp[e] *= isum;
    float4 p0 = {pp[0], pp[1], pp[2], pp[3]};
    float4 p1 = {pp[4], pp[5], pp[6], pp[7]};
    *(float4*)&probs[(size_t)t * E_] = p0;
    *(float4*)&probs[(size_t)t * E_ + 4] = p1;
    int e0 = 0; float b0 = pp[0];
    #pragma unroll
    for (int e = 1; e < E_; e++) if (pp[e] > b0) { b0 = pp[e]; e0 = e; }
    int e1 = -1; float b1 = -1.f;
    #pragma unroll
    for (int e = 0; e < E_; e++) if (e != e0 && pp[e] > b1) { b1 = pp[e]; e1 = e; }
    const float iw = 1.f / (b0 + b1);
    texp[2 * t] = e0; texp[2 * t + 1] = e1;
    tw[2 * t] = b0 * iw; tw[2 * t + 1] = b1 * iw;
  }
}

__global__ __launch_bounds__(256) void fill_slots(int* slot_tok, float* slot_w) {
  const int i = blockIdx.x * 256 + threadIdx.x;
  if (i < PADSLOTS) { slot_tok[i] = -1; slot_w[i] = 0.f; }
}

// ------------------------------------------- finalize: reduce + build + scatter
__global__ __launch_bounds__(256) void finalize_kernel(const float* __restrict__ probs,
                                                       const int* __restrict__ texp,
                                                       const float* __restrict__ tw,
                                                       int* __restrict__ ntiles,
                                                       int* __restrict__ tile_expert,
                                                       int* __restrict__ slot_tok,
                                                       float* __restrict__ slot_w,
                                                       float* __restrict__ lb_out) {
  const int tid = threadIdx.x;
  const int w = tid >> 6, lane = tid & 63;
  __shared__ float sRed[4][E_];
  __shared__ int sCnt[4][E_];
  __shared__ int sPoff[E_];
  __shared__ int sBase[E_];
  __shared__ int sWcnt[4][E_];

  float ps[E_];
  #pragma unroll
  for (int e = 0; e < E_; e++) ps[e] = 0.f;
  #pragma unroll
  for (int i = 0; i < T_ / 256; i++) {
    const float4* pr = (const float4*)&probs[(size_t)(i * 256 + tid) * E_];
    const float4 a = pr[0], b = pr[1];
    ps[0] += a.x; ps[1] += a.y; ps[2] += a.z; ps[3] += a.w;
    ps[4] += b.x; ps[5] += b.y; ps[6] += b.z; ps[7] += b.w;
  }
  #pragma unroll
  for (int e = 0; e < E_; e++) {
    #pragma unroll
    for (int off = 32; off; off >>= 1) ps[e] += __shfl_xor(ps[e], off);
  }
  int cnt[E_];
  #pragma unroll
  for (int e = 0; e < E_; e++) cnt[e] = 0;
  #pragma unroll
  for (int i = 0; i < 2 * T_ / 256; i++) {
    const int ee = texp[i * 256 + tid];
    #pragma unroll
    for (int e = 0; e < E_; e++) cnt[e] += (ee == e) ? 1 : 0;
  }
  #pragma unroll
  for (int e = 0; e < E_; e++) {
    #pragma unroll
    for (int off = 32; off; off >>= 1) cnt[e] += __shfl_xor(cnt[e], off);
  }
  if (lane == 0) {
    #pragma unroll
    for (int e = 0; e < E_; e++) { sRed[w][e] = ps[e]; sCnt[w][e] = cnt[e]; }
  }
  __syncthreads();
  if (tid == 0) {
    int off = 0, tc = 0;
    float lb = 0.f;
    for (int e = 0; e < E_; e++) {
      const int c = sCnt[0][e] + sCnt[1][e] + sCnt[2][e] + sCnt[3][e];
      const float p = sRed[0][e] + sRed[1][e] + sRed[2][e] + sRed[3][e];
      sPoff[e] = off;
      const int nt = (c + 127) >> 7;
      for (int i = 0; i < nt; i++) tile_expert[tc++] = e;
      off += nt << 7;
      lb += ((float)c / (float)T_) * (p / (float)T_);
    }
    *ntiles = tc;
    lb_out[0] = lb * (float)E_;
  }
  if (tid < E_) sBase[tid] = 0;
  __syncthreads();
  for (int c = 0; c < 2 * T_ / 256; c++) {
    const int i = c * 256 + tid;
    const int e = texp[i];
    const float wv = tw[i];
    int myrank = 0;
    #pragma unroll
    for (int ee = 0; ee < E_; ee++) {
      const unsigned long long m = __ballot(e == ee);
      if (lane == 0) sWcnt[w][ee] = (int)__popcll(m);
      if (e == ee) myrank = (int)__popcll(m & ((1ull << lane) - 1ull));
    }
    __syncthreads();
    int pre = 0;
    #pragma unroll
    for (int w2 = 0; w2 < 4; w2++) if (w2 < w) pre += sWcnt[w2][e];
    const int slot = sPoff[e] + sBase[e] + pre + myrank;
    slot_tok[slot] = i >> 1;
    slot_w[slot] = wv;
    __syncthreads();
    if (tid < E_) sBase[tid] += sWcnt[0][tid] + sWcnt[1][tid] + sWcnt[2][tid] + sWcnt[3][tid];
    __syncthreads();
  }
}

// --------------------------- MoE GEMM1 (MFMA): h = silu(x@Wg^T)*(x@Wu^T)
// fp32 weights read DIRECTLY; in-loop f2bf staging; bounds (256,3) -> 3 blk/CU.
// XCD-aligned flat grid: bid = tile*64 + n0idx -> XCD = n0idx%8 (L2 weight reuse).
// BK=64, LDA=72.
__global__ __launch_bounds__(256, 3) void moe_gemm1(const unsigned short* __restrict__ x2b,
                                                    const float* __restrict__ Wg,
                                                    const float* __restrict__ Wu,
                                                    const int* __restrict__ slot_tok,
                                                    const int* __restrict__ tile_expert,
                                                    const int* __restrict__ ntiles,
                                                    unsigned short* __restrict__ hbuf) {
  const int bid = blockIdx.x;
  const int tile = bid >> 6;
  const int n0 = (bid & 63) << 6;
  if (tile >= *ntiles) return;
  constexpr int K = 1024;
  constexpr int LDA = 72;
  __shared__ __align__(16) unsigned short sA[128 * LDA];
  __shared__ __align__(16) unsigned short sG[64 * LDA];
  __shared__ __align__(16) unsigned short sU[64 * LDA];
  __shared__ int stok[128];
  const int tid = threadIdx.x;
  if (tid < 128) stok[tid] = slot_tok[tile * 128 + tid];
  __syncthreads();
  const int e = tile_expert[tile];
  const int wave = tid >> 6, lane = tid & 63, wm = wave >> 1, wn = wave & 1;
  const int g16 = lane >> 4, l15 = lane & 15;
  const int arow = tid >> 2, akq = (tid & 3) << 4;
  const int grow = tid >> 2, gkq = (tid & 3) << 3;
  int tok0 = stok[arow];       if (tok0 < 0) tok0 = 0;
  int tok1 = stok[64 + arow];  if (tok1 < 0) tok1 = 0;
  const unsigned short* a0 = x2b + (size_t)tok0 * K + akq;
  const unsigned short* a1 = x2b + (size_t)tok1 * K + akq;
  const float* gp = Wg + ((size_t)e * FF_ + n0 + grow) * K + gkq;
  const float* up = Wu + ((size_t)e * FF_ + n0 + grow) * K + gkq;

  f32x4 ag[4][2], au[4][2];
  #pragma unroll
  for (int m = 0; m < 4; m++)
    #pragma unroll
    for (int n = 0; n < 2; n++) { ag[m][n] = (f32x4){0,0,0,0}; au[m][n] = (f32x4){0,0,0,0}; }

  uint4 ra0 = *(const uint4*)a0, ra1 = *(const uint4*)(a0 + 8);
  uint4 ra2 = *(const uint4*)a1, ra3 = *(const uint4*)(a1 + 8);
  float4 rg[4], ru[4];
  rg[0] = *(const float4*)gp;        rg[1] = *(const float4*)(gp + 4);
  rg[2] = *(const float4*)(gp + 32); rg[3] = *(const float4*)(gp + 36);
  ru[0] = *(const float4*)up;        ru[1] = *(const float4*)(up + 4);
  ru[2] = *(const float4*)(up + 32); ru[3] = *(const float4*)(up + 36);

  for (int k0 = 0; k0 < K; k0 += 64) {
    __align__(16) unsigned short tg[16], tu[16];
    cvt8(rg[0], rg[1], tg); cvt8(rg[2], rg[3], tg + 8);
    cvt8(ru[0], ru[1], tu); cvt8(ru[2], ru[3], tu + 8);
    __syncthreads();
    *(uint4*)&sA[arow * LDA + akq] = ra0;
    *(uint4*)&sA[arow * LDA + akq + 8] = ra1;
    *(uint4*)&sA[(arow + 64) * LDA + akq] = ra2;
    *(uint4*)&sA[(arow + 64) * LDA + akq + 8] = ra3;
    *(uint4*)&sG[grow * LDA + gkq] = ((const uint4*)tg)[0];
    *(uint4*)&sG[grow * LDA + gkq + 32] = ((const uint4*)tg)[1];
    *(uint4*)&sU[grow * LDA + gkq] = ((const uint4*)tu)[0];
    *(uint4*)&sU[grow * LDA + gkq + 32] = ((const uint4*)tu)[1];
    // prefetch next phase BEFORE barrier2
    if (k0 + 64 < K) {
      ra0 = *(const uint4*)(a0 + k0 + 64); ra1 = *(const uint4*)(a0 + k0 + 72);
      ra2 = *(const uint4*)(a1 + k0 + 64); ra3 = *(const uint4*)(a1 + k0 + 72);
      rg[0] = *(const float4*)(gp + k0 + 64); rg[1] = *(const float4*)(gp + k0 + 68);
      rg[2] = *(const float4*)(gp + k0 + 96); rg[3] = *(const float4*)(gp + k0 + 100);
      ru[0] = *(const float4*)(up + k0 + 64); ru[1] = *(const float4*)(up + k0 + 68);
      ru[2] = *(const float4*)(up + k0 + 96); ru[3] = *(const float4*)(up + k0 + 100);
    }
    __syncthreads();
    #pragma unroll
    for (int ks = 0; ks < 2; ks++) {
      const int ko = ks * 32 + g16 * 8;
      short8 af[4], gf[2], uf[2];
      #pragma unroll
      for (int m = 0; m < 4; m++)
        af[m] = *(const short8*)&sA[(wm * 64 + m * 16 + l15) * LDA + ko];
      #pragma unroll
      for (int n = 0; n < 2; n++) {
        gf[n] = *(const short8*)&sG[(wn * 32 + n * 16 + l15) * LDA + ko];
        uf[n] = *(const short8*)&sU[(wn * 32 + n * 16 + l15) * LDA + ko];
      }
      #pragma unroll
      for (int m = 0; m < 4; m++)
        #pragma unroll
        for (int n = 0; n < 2; n++) {
          ag[m][n] = __builtin_amdgcn_mfma_f32_16x16x32_bf16(af[m], gf[n], ag[m][n], 0, 0, 0);
          au[m][n] = __builtin_amdgcn_mfma_f32_16x16x32_bf16(af[m], uf[n], au[m][n], 0, 0, 0);
        }
    }
  }
  #pragma unroll
  for (int m = 0; m < 4; m++)
    #pragma unroll
    for (int r = 0; r < 4; r++) {
      const int slotloc = wm * 64 + m * 16 + g16 * 4 + r;
      unsigned short* hr = hbuf + (size_t)(tile * 128 + slotloc) * FF_ + n0;
      #pragma unroll
      for (int n = 0; n < 2; n++) {
        const int col = wn * 32 + n * 16 + l15;
        const float g = ag[m][n][r], u = au[m][n][r];
        const float hv = (g / (1.f + __expf(-g))) * u;
        hr[col] = f2bf(hv);
      }
    }
}

// --------------------------- MoE GEMM2 (MFMA): out += w * (h @ Wd^T)
// bf16 mirror Wdb, BK=64, LDA=72. hbuf-coherent flat grid; bounds (256,3).
__global__ __launch_bounds__(256, 3) void moe_gemm2(const unsigned short* __restrict__ hbuf,
                                                    const unsigned short* __restrict__ Wdb,
                                                    const int* __restrict__ slot_tok,
                                                    const float* __restrict__ slot_w,
                                                    const int* __restrict__ tile_expert,
                                                    const int* __restrict__ ntiles,
                                                    float* __restrict__ out) {
  const int bid = blockIdx.x;
  const int tile = bid % MAXTILES;
  const int n0 = (bid / MAXTILES) << 7;
  if (tile >= *ntiles) return;
  constexpr int K = 4096;
  constexpr int LDA = 72;
  __shared__ __align__(16) unsigned short sA[128 * LDA];
  __shared__ __align__(16) unsigned short sB[128 * LDA];
  __shared__ int s_tok[128];
  __shared__ float s_w[128];
  const int tid = threadIdx.x;
  if (tid < 128) { s_tok[tid] = slot_tok[tile * 128 + tid]; s_w[tid] = slot_w[tile * 128 + tid]; }
  const int e = tile_expert[tile];
  const int wave = tid >> 6, lane = tid & 63, wm = wave >> 1, wn = wave & 1;
  const int g16 = lane >> 4, l15 = lane & 15;
  const int arow = tid >> 1, akq = (tid & 1) << 4;
  const unsigned short* ap = hbuf + (size_t)(tile * 128 + arow) * K + akq;
  const unsigned short* wp = Wdb + ((size_t)e * H_ + n0 + arow) * K + akq;

  f32x4 acc[4][4];
  #pragma unroll
  for (int m = 0; m < 4; m++)
    #pragma unroll
    for (int n = 0; n < 4; n++) acc[m][n] = (f32x4){0,0,0,0};

  uint4 ra0 = *(const uint4*)ap, ra1 = *(const uint4*)(ap + 8);
  uint4 ra2 = *(const uint4*)(ap + 32), ra3 = *(const uint4*)(ap + 40);
  uint4 rb0 = *(const uint4*)wp, rb1 = *(const uint4*)(wp + 8);
  uint4 rb2 = *(const uint4*)(wp + 32), rb3 = *(const uint4*)(wp + 40);

  for (int k0 = 0; k0 < K; k0 += 64) {
    __syncthreads();
    *(uint4*)&sA[arow * LDA + akq] = ra0;
    *(uint4*)&sA[arow * LDA + akq + 8] = ra1;
    *(uint4*)&sA[arow * LDA + akq + 32] = ra2;
    *(uint4*)&sA[arow * LDA + akq + 40] = ra3;
    *(uint4*)&sB[arow * LDA + akq] = rb0;
    *(uint4*)&sB[arow * LDA + akq + 8] = rb1;
    *(uint4*)&sB[arow * LDA + akq + 32] = rb2;
    *(uint4*)&sB[arow * LDA + akq + 40] = rb3;
    // prefetch next phase BEFORE barrier2
    if (k0 + 64 < K) {
      ra0 = *(const uint4*)(ap + k0 + 64); ra1 = *(const uint4*)(ap + k0 + 72);
      ra2 = *(const uint4*)(ap + k0 + 96); ra3 = *(const uint4*)(ap + k0 + 104);
      rb0 = *(const uint4*)(wp + k0 + 64); rb1 = *(const uint4*)(wp + k0 + 72);
      rb2 = *(const uint4*)(wp + k0 + 96); rb3 = *(const uint4*)(wp + k0 + 104);
    }
    __syncthreads();
    #pragma unroll
    for (int ks = 0; ks < 2; ks++) {
      const int ko = ks * 32 + g16 * 8;
      short8 af[4], bf_[4];
      #pragma unroll
      for (int m = 0; m < 4; m++)
        af[m] = *(const short8*)&sA[(wm * 64 + m * 16 + l15) * LDA + ko];
      #pragma unroll
      for (int n = 0; n < 4; n++)
        bf_[n] = *(const short8*)&sB[(wn * 64 + n * 16 + l15) * LDA + ko];
      #pragma unroll
      for (int m = 0; m < 4; m++)
        #pragma unroll
        for (int n = 0; n < 4; n++)
          acc[m][n] = __builtin_amdgcn_mfma_f32_16x16x32_bf16(af[m], bf_[n], acc[m][n], 0, 0, 0);
    }
  }
  #pragma unroll
  for (int m = 0; m < 4; m++)
    #pragma unroll
    for (int r = 0; r < 4; r++) {
      const int slotloc = wm * 64 + m * 16 + g16 * 4 + r;
      const int tok = s_tok[slotloc];
      if (tok < 0) continue;
      const float wv = s_w[slotloc];
      float* orow = out + (size_t)tok * H_ + n0;
      #pragma unroll
      for (int n = 0; n < 4; n++) {
        const int col = wn * 64 + n * 16 + l15;
        atomicAdd(&orow[col], wv * acc[m][n][r]);
      }
    }
}

}  // namespace

extern "C" void kernel_launch(void* const* d_in, const int* in_sizes, int n_in,
                              void* d_out, int out_size, void* d_ws, size_t ws_size,
                              hipStream_t stream) {
  const float* hs  = (const float*)d_in[0];
  const float* ln1 = (const float*)d_in[2];
  const float* ln2 = (const float*)d_in[3];
  const float* Wq  = (const float*)d_in[4];
  const float* Wk  = (const float*)d_in[5];
  const float* Wv  = (const float*)d_in[6];
  const float* Wo  = (const float*)d_in[7];
  const float* Wr  = (const float*)d_in[8];
  const float* Wg  = (const float*)d_in[9];
  const float* Wu  = (const float*)d_in[10];
  const float* Wd  = (const float*)d_in[11];
  float* out = (float*)d_out;
  char* ws = (char*)d_ws;

  constexpr size_t MB = (size_t)1 << 20;
  unsigned short* x1s = (unsigned short*)(ws);             // 8 MiB (hi+lo planes)
  float* qb  = (float*)(ws + 8 * MB);                      // 8 MiB
  float* kb  = (float*)(ws + 16 * MB);
  float* vb  = (float*)(ws + 24 * MB);
  unsigned short* aos = (unsigned short*)(ws + 32 * MB);   // 8 MiB (hi+lo planes)
  float* x2  = (float*)(ws + 40 * MB);                     // 8 MiB
  unsigned short* x2b  = (unsigned short*)(ws + 48 * MB);  // 4 MiB
  unsigned short* hbuf = (unsigned short*)(ws + 52 * MB);  // 40 MiB
  // QKV/O weight splits live INSIDE hbuf region (dead before moe_gemm1 writes)
  unsigned short* wqs = (unsigned short*)(ws + 52 * MB);   // 4 MiB each
  unsigned short* wks = (unsigned short*)(ws + 56 * MB);
  unsigned short* wvs = (unsigned short*)(ws + 60 * MB);
  unsigned short* wos = (unsigned short*)(ws + 64 * MB);
  char* meta = ws + 92 * MB;
  int*   ntl     = (int*)(meta + 256);
  int*   texpert = (int*)(meta + 512);
  int*   texp    = (int*)(meta + 1024);
  float* tw      = (float*)(meta + 1024 + 16384);
  int*   stok    = (int*)(meta + 1024 + 32768);
  float* sw      = (float*)(meta + 1024 + 32768 + (size_t)PADSLOTS * 4);
  float* probs   = (float*)(meta + 1024 + 32768 + (size_t)PADSLOTS * 8);
  constexpr size_t WELEMS = (size_t)E_ * FF_ * H_;   // 33,554,432
  unsigned short* wdb = (unsigned short*)(ws + 96 * MB);   // 64 MiB Wd bf16 mirror

  // split QKV/O weights (one-time per call; L2-sized, ~6 us)
  const int wblk = (int)(WPL / 8 / 256);   // 512
  cvt_wsplit<<<dim3(wblk), 256, 0, stream>>>(Wq, wqs, (int)(WPL / 8));
  cvt_wsplit<<<dim3(wblk), 256, 0, stream>>>(Wk, wks, (int)(WPL / 8));
  cvt_wsplit<<<dim3(wblk), 256, 0, stream>>>(Wv, wvs, (int)(WPL / 8));
  cvt_wsplit<<<dim3(wblk), 256, 0, stream>>>(Wo, wos, (int)(WPL / 8));

  rmsnorm_kernel<2><<<dim3(T_), dim3(256), 0, stream>>>(hs, ln1, nullptr, x1s);

  gemm_split<0><<<dim3(16, 8, 3), 256, 0, stream>>>(x1s, wqs, wks, wvs, qb, kb, vb, nullptr);

  const int rope_blocks = (T_ * NH_ * 32) / 256;
  rope_kernel<<<dim3(rope_blocks), 256, 0, stream>>>(qb);
  rope_kernel<<<dim3(rope_blocks), 256, 0, stream>>>(kb);

  attn_mfma<<<dim3(B_ * NH_ * (S_ / 128)), 512, 0, stream>>>(qb, kb, vb, aos);

  gemm_wo<<<dim3(16, 8), 256, 0, stream>>>(aos, wos, out, hs);

  rmsnorm_kernel<1><<<dim3(T_), dim3(256), 0, stream>>>(out, ln2, x2, x2b);
  router_kernel<<<dim3(T_ / 4), 256, 0, stream>>>(x2, Wr, probs, texp, tw);
  fill_slots<<<dim3(PADSLOTS / 256), 256, 0, stream>>>(stok, sw);
  finalize_kernel<<<dim3(1), dim3(256), 0, stream>>>(probs, texp, tw, ntl, texpert,
                                                     stok, sw, out + (size_t)T_ * H_);

  moe_gemm1<<<dim3(MAXTILES * (FF_ / 64)), 256, 0, stream>>>(x2b, Wg, Wu, stok, texpert, ntl, hbuf);

  // Wd bf16 mirror right before gemm2 (leaves wdb L3-hot)
  const int cvt_blocks = (int)(WELEMS / 8 / 256);   // 16384
  cvt_ws<<<dim3(cvt_blocks), 256, 0, stream>>>(Wd, wdb, (int)(WELEMS / 8));

  moe_gemm2<<<dim3(MAXTILES * (H_ / 128)), 256, 0, stream>>>(hbuf, wdb, stok, sw, texpert, ntl, out);
}

// Round 21
// 468.782 us; speedup vs baseline: 1.0197x; 1.0197x over previous
//
#include <hip/hip_runtime.h>
#include <cstdint>
#include <cstddef>

#define DI __device__ __forceinline__

namespace {

constexpr int B_ = 2, S_ = 1024, H_ = 1024, NH_ = 16, FF_ = 4096, E_ = 8;
constexpr int T_ = B_ * S_;                     // 2048 tokens
constexpr int MAXTILES = (T_ * 2) / 128 + E_;   // 40 row-tiles (128 slots each)
constexpr int PADSLOTS = MAXTILES * 128;        // 5120 slots
constexpr size_t APL = (size_t)T_ * H_;         // activation plane offset
constexpr size_t WPL = (size_t)H_ * H_;         // weight plane offset

typedef __attribute__((ext_vector_type(8))) short short8;
typedef __attribute__((ext_vector_type(4))) float f32x4;

DI float bf2f(unsigned short u) { return __uint_as_float(((unsigned)u) << 16); }
DI unsigned short f2bf(float f) {
  unsigned u = __float_as_uint(f);
  u += 0x7fffu + ((u >> 16) & 1u);
  return (unsigned short)(u >> 16);
}
// convert 8 floats (two float4) -> 8 bf16
DI void cvt8(const float4 a, const float4 b, unsigned short* d) {
  d[0] = f2bf(a.x); d[1] = f2bf(a.y); d[2] = f2bf(a.z); d[3] = f2bf(a.w);
  d[4] = f2bf(b.x); d[5] = f2bf(b.y); d[6] = f2bf(b.z); d[7] = f2bf(b.w);
}

// ---------------------------------------------------------------- RMSNorm
// MODE 1: fp32 out + single bf16 outb.   MODE 2: hi/lo split planes in outb.
template <int MODE>
__global__ __launch_bounds__(256) void rmsnorm_kernel(const float* __restrict__ in,
                                                      const float* __restrict__ w,
                                                      float* __restrict__ out,
                                                      unsigned short* __restrict__ outb) {
  const int t = blockIdx.x, tid = threadIdx.x;
  const float4* row = (const float4*)(in + (size_t)t * H_);
  float4 v = row[tid];
  float ss = v.x * v.x + v.y * v.y + v.z * v.z + v.w * v.w;
  #pragma unroll
  for (int off = 32; off; off >>= 1) ss += __shfl_down(ss, off);
  __shared__ float red[4];
  if ((tid & 63) == 0) red[tid >> 6] = ss;
  __syncthreads();
  const float total = red[0] + red[1] + red[2] + red[3];
  const float rinv = 1.f / sqrtf(total * (1.f / (float)H_) + 1e-6f);
  const float4 wv = ((const float4*)w)[tid];
  float o[4];
  o[0] = v.x * rinv * wv.x; o[1] = v.y * rinv * wv.y;
  o[2] = v.z * rinv * wv.z; o[3] = v.w * rinv * wv.w;
  if (MODE == 1) {
    float4 o4 = {o[0], o[1], o[2], o[3]};
    ((float4*)(out + (size_t)t * H_))[tid] = o4;
    unsigned short* p = outb + (size_t)t * H_ + tid * 4;
    p[0] = f2bf(o[0]); p[1] = f2bf(o[1]); p[2] = f2bf(o[2]); p[3] = f2bf(o[3]);
  } else {
    __align__(8) unsigned short hi[4], lo[4];
    #pragma unroll
    for (int j = 0; j < 4; j++) {
      hi[j] = f2bf(o[j]);
      lo[j] = f2bf(o[j] - bf2f(hi[j]));
    }
    const size_t idx = (size_t)t * H_ + tid * 4;
    *(uint2*)&outb[idx] = *(const uint2*)hi;
    *(uint2*)&outb[APL + idx] = *(const uint2*)lo;
  }
}

// ---------------------------------------- fp32 weight -> hi/lo bf16 planes
__global__ __launch_bounds__(256) void cvt_wsplit(const float* __restrict__ src,
                                                  unsigned short* __restrict__ dst, int n8) {
  const int i = blockIdx.x * 256 + threadIdx.x;
  if (i < n8) {
    const float4 a = ((const float4*)src)[2 * i];
    const float4 b = ((const float4*)src)[2 * i + 1];
    const float xs[8] = {a.x, a.y, a.z, a.w, b.x, b.y, b.z, b.w};
    __align__(16) unsigned short hi[8], lo[8];
    #pragma unroll
    for (int j = 0; j < 8; j++) {
      hi[j] = f2bf(xs[j]);
      lo[j] = f2bf(xs[j] - bf2f(hi[j]));
    }
    ((uint4*)dst)[i] = *(const uint4*)hi;
    ((uint4*)(dst + WPL))[i] = *(const uint4*)lo;
  }
}

// ---------------------------------------------------- fp32 -> bf16 convert
__global__ __launch_bounds__(256) void cvt_ws(const float* __restrict__ src,
                                              unsigned short* __restrict__ dst, int n8) {
  const int i = blockIdx.x * 256 + threadIdx.x;
  if (i < n8) {
    const float4 a = ((const float4*)src)[2 * i];
    const float4 b = ((const float4*)src)[2 * i + 1];
    __align__(16) unsigned short t[8];
    cvt8(a, b, t);
    ((uint4*)dst)[i] = *(const uint4*)t;
  }
}

// ------------------------- planar split-bf16 MFMA NT GEMM (pure bf16 staging)
template <int EPI>
__global__ __launch_bounds__(256, 3) void gemm_split(const unsigned short* __restrict__ As,
                                                     const unsigned short* __restrict__ Wsa,
                                                     const unsigned short* __restrict__ Wsb,
                                                     const unsigned short* __restrict__ Wsc,
                                                     float* __restrict__ Ca,
                                                     float* __restrict__ Cb,
                                                     float* __restrict__ Cc,
                                                     const float* __restrict__ resid) {
  constexpr int K = 1024;
  constexpr int LDA = 40;
  __shared__ __align__(16) unsigned short sAh[128 * LDA];
  __shared__ __align__(16) unsigned short sAl[128 * LDA];
  __shared__ __align__(16) unsigned short sWh[128 * LDA];
  __shared__ __align__(16) unsigned short sWl[128 * LDA];
  const int tid = threadIdx.x;
  const int m0 = blockIdx.x << 7, n0 = blockIdx.y << 7;
  const unsigned short* W = Wsa; float* C = Ca;
  if (EPI == 0) {
    if (blockIdx.z == 1) { W = Wsb; C = Cb; }
    else if (blockIdx.z == 2) { W = Wsc; C = Cc; }
  }
  const int wave = tid >> 6, lane = tid & 63, wm = wave >> 1, wn = wave & 1;
  const int g16 = lane >> 4, l15 = lane & 15;
  const int row = tid >> 1, kq = (tid & 1) << 4;
  const unsigned short* pah = As + (size_t)(m0 + row) * K + kq;
  const unsigned short* pal = pah + APL;
  const unsigned short* pwh = W + (size_t)(n0 + row) * K + kq;
  const unsigned short* pwl = pwh + WPL;
  f32x4 acc[4][4];
  #pragma unroll
  for (int m = 0; m < 4; m++)
    #pragma unroll
    for (int n = 0; n < 4; n++) acc[m][n] = (f32x4){0.f, 0.f, 0.f, 0.f};

  uint4 rah0 = *(const uint4*)pah, rah1 = *(const uint4*)(pah + 8);
  uint4 ral0 = *(const uint4*)pal, ral1 = *(const uint4*)(pal + 8);
  uint4 rwh0 = *(const uint4*)pwh, rwh1 = *(const uint4*)(pwh + 8);
  uint4 rwl0 = *(const uint4*)pwl, rwl1 = *(const uint4*)(pwl + 8);

  for (int k0 = 0; k0 < K; k0 += 32) {
    __syncthreads();
    *(uint4*)&sAh[row * LDA + kq] = rah0;
    *(uint4*)&sAh[row * LDA + kq + 8] = rah1;
    *(uint4*)&sAl[row * LDA + kq] = ral0;
    *(uint4*)&sAl[row * LDA + kq + 8] = ral1;
    *(uint4*)&sWh[row * LDA + kq] = rwh0;
    *(uint4*)&sWh[row * LDA + kq + 8] = rwh1;
    *(uint4*)&sWl[row * LDA + kq] = rwl0;
    *(uint4*)&sWl[row * LDA + kq + 8] = rwl1;
    // prefetch next phase BEFORE barrier2: loads in flight across barrier + MFMA
    if (k0 + 32 < K) {
      rah0 = *(const uint4*)(pah + k0 + 32); rah1 = *(const uint4*)(pah + k0 + 40);
      ral0 = *(const uint4*)(pal + k0 + 32); ral1 = *(const uint4*)(pal + k0 + 40);
      rwh0 = *(const uint4*)(pwh + k0 + 32); rwh1 = *(const uint4*)(pwh + k0 + 40);
      rwl0 = *(const uint4*)(pwl + k0 + 32); rwl1 = *(const uint4*)(pwl + k0 + 40);
    }
    __syncthreads();
    short8 ah[4], al[4], wh[4], wl[4];
    #pragma unroll
    for (int m = 0; m < 4; m++) {
      ah[m] = *(const short8*)&sAh[(wm * 64 + m * 16 + l15) * LDA + g16 * 8];
      al[m] = *(const short8*)&sAl[(wm * 64 + m * 16 + l15) * LDA + g16 * 8];
    }
    #pragma unroll
    for (int n = 0; n < 4; n++) {
      wh[n] = *(const short8*)&sWh[(wn * 64 + n * 16 + l15) * LDA + g16 * 8];
      wl[n] = *(const short8*)&sWl[(wn * 64 + n * 16 + l15) * LDA + g16 * 8];
    }
    #pragma unroll
    for (int m = 0; m < 4; m++)
      #pragma unroll
      for (int n = 0; n < 4; n++) {
        acc[m][n] = __builtin_amdgcn_mfma_f32_16x16x32_bf16(ah[m], wh[n], acc[m][n], 0, 0, 0);
        acc[m][n] = __builtin_amdgcn_mfma_f32_16x16x32_bf16(al[m], wh[n], acc[m][n], 0, 0, 0);
        acc[m][n] = __builtin_amdgcn_mfma_f32_16x16x32_bf16(ah[m], wl[n], acc[m][n], 0, 0, 0);
      }
  }
  #pragma unroll
  for (int m = 0; m < 4; m++)
    #pragma unroll
    for (int r = 0; r < 4; r++) {
      const int grow = m0 + wm * 64 + m * 16 + g16 * 4 + r;
      #pragma unroll
      for (int n = 0; n < 4; n++) {
        const int gcol = n0 + wn * 64 + n * 16 + l15;
        float v = acc[m][n][r];
        if (EPI == 1) v += resid[(size_t)grow * 1024 + gcol];
        C[(size_t)grow * 1024 + gcol] = v;
      }
    }
}

// ---------------------------------------------------------------- RoPE (fp32, [t][h*64+d])
__global__ __launch_bounds__(256) void rope_kernel(float* __restrict__ buf) {
  const int id = blockIdx.x * 256 + threadIdx.x;  // T_*NH_*32 total
  const int t = id >> 9;
  const int rem = id & 511;
  const int h = rem >> 5, j = rem & 31;
  const int s = t & (S_ - 1);
  const float inv = exp2f(-(float)j * (0.41524101186092029f));
  const float ang = (float)s * inv;
  const float c = cosf(ang), sn = sinf(ang);
  float* p = buf + (size_t)t * H_ + h * 64;
  const float xa = p[j], xb = p[j + 32];
  p[j] = xa * c - xb * sn;
  p[j + 32] = xb * c + xa * sn;
}

// ------------------------------------------------- flash attention, split-bf16 MFMA
__global__ __launch_bounds__(512, 2) void attn_mfma(const float* __restrict__ q,
                                                    const float* __restrict__ k,
                                                    const float* __restrict__ v,
                                                    unsigned short* __restrict__ aos) {
  constexpr int LDW = 136;  // ushort stride (128 + 8 pad)
  __shared__ __align__(16) unsigned short sP[128 * LDW];   // Q staging, then P
  __shared__ __align__(16) unsigned short sK[64 * LDW];
  __shared__ __align__(16) unsigned short sVt[64 * LDW];
  const int tid = threadIdx.x;
  const int bh = blockIdx.x >> 3, chunk = blockIdx.x & 7;
  const int b = bh >> 4, h = bh & (NH_ - 1);
  const int w = tid >> 6, lane = tid & 63, g = lane >> 4, l15 = lane & 15;

  {
    const int row = tid >> 2, d0 = (tid & 3) << 4;
    const float* qp = q + ((size_t)((b << 10) + (chunk << 7) + row)) * H_ + h * 64 + d0;
    __align__(16) unsigned short thi[16], tlo[16];
    #pragma unroll
    for (int c = 0; c < 4; c++) {
      const float4 x = ((const float4*)qp)[c];
      const float xs[4] = {x.x, x.y, x.z, x.w};
      #pragma unroll
      for (int j = 0; j < 4; j++) {
        const float val = xs[j] * 0.125f;
        const unsigned short hi = f2bf(val);
        thi[c * 4 + j] = hi;
        tlo[c * 4 + j] = f2bf(val - bf2f(hi));
      }
    }
    uint4* dh = (uint4*)&sP[row * LDW + d0];
    dh[0] = ((const uint4*)thi)[0]; dh[1] = ((const uint4*)thi)[1];
    uint4* dl = (uint4*)&sP[row * LDW + 64 + d0];
    dl[0] = ((const uint4*)tlo)[0]; dl[1] = ((const uint4*)tlo)[1];
  }
  __syncthreads();
  short8 aqh[2], aql[2];
  #pragma unroll
  for (int s2 = 0; s2 < 2; s2++) {
    aqh[s2] = *(const short8*)&sP[(w * 16 + l15) * LDW + s2 * 32 + g * 8];
    aql[s2] = *(const short8*)&sP[(w * 16 + l15) * LDW + 64 + s2 * 32 + g * 8];
  }
  __syncthreads();

  f32x4 accO[4];
  #pragma unroll
  for (int n = 0; n < 4; n++) accO[n] = (f32x4){0.f, 0.f, 0.f, 0.f};
  float mrun[4] = {-3.0e38f, -3.0e38f, -3.0e38f, -3.0e38f};
  float lrun[4] = {0.f, 0.f, 0.f, 0.f};

  const int krow = tid >> 3, dk0 = (tid & 7) << 3;
  const int vd = tid >> 3, vk0 = (tid & 7) << 3;
  const float* kp0 = k + ((size_t)((b << 10) + krow)) * H_ + h * 64 + dk0;
  const float* vp0 = v + ((size_t)(b << 10)) * H_ + h * 64 + vd;

  float krg[8], vrg[8];
  {
    const float4 a = *(const float4*)kp0;
    const float4 c = *(const float4*)(kp0 + 4);
    krg[0] = a.x; krg[1] = a.y; krg[2] = a.z; krg[3] = a.w;
    krg[4] = c.x; krg[5] = c.y; krg[6] = c.z; krg[7] = c.w;
    #pragma unroll
    for (int i = 0; i < 8; i++) vrg[i] = vp0[(size_t)(vk0 + i) * H_];
  }
  {
    __align__(16) unsigned short thi[8], tlo[8];
    #pragma unroll
    for (int j = 0; j < 8; j++) {
      const unsigned short hi = f2bf(krg[j]);
      thi[j] = hi; tlo[j] = f2bf(krg[j] - bf2f(hi));
    }
    *(uint4*)&sK[krow * LDW + dk0] = *(const uint4*)thi;
    *(uint4*)&sK[krow * LDW + 64 + dk0] = *(const uint4*)tlo;
    #pragma unroll
    for (int j = 0; j < 8; j++) {
      const unsigned short hi = f2bf(vrg[j]);
      thi[j] = hi; tlo[j] = f2bf(vrg[j] - bf2f(hi));
    }
    *(uint4*)&sVt[vd * LDW + vk0] = *(const uint4*)thi;
    *(uint4*)&sVt[vd * LDW + 64 + vk0] = *(const uint4*)tlo;
  }
  __syncthreads();

  for (int kt = 0; kt < S_ / 64; kt++) {
    if (kt < S_ / 64 - 1) {
      const float* kp = kp0 + (size_t)((kt + 1) * 64) * H_;
      const float4 a = *(const float4*)kp;
      const float4 c = *(const float4*)(kp + 4);
      krg[0] = a.x; krg[1] = a.y; krg[2] = a.z; krg[3] = a.w;
      krg[4] = c.x; krg[5] = c.y; krg[6] = c.z; krg[7] = c.w;
      #pragma unroll
      for (int i = 0; i < 8; i++) vrg[i] = vp0[(size_t)((kt + 1) * 64 + vk0 + i) * H_];
    }
    f32x4 accS[4];
    #pragma unroll
    for (int n = 0; n < 4; n++) accS[n] = (f32x4){0.f, 0.f, 0.f, 0.f};
    #pragma unroll
    for (int s2 = 0; s2 < 2; s2++) {
      #pragma unroll
      for (int n = 0; n < 4; n++) {
        const short8 bkh = *(const short8*)&sK[(n * 16 + l15) * LDW + s2 * 32 + g * 8];
        const short8 bkl = *(const short8*)&sK[(n * 16 + l15) * LDW + 64 + s2 * 32 + g * 8];
        accS[n] = __builtin_amdgcn_mfma_f32_16x16x32_bf16(aqh[s2], bkh, accS[n], 0, 0, 0);
        accS[n] = __builtin_amdgcn_mfma_f32_16x16x32_bf16(aql[s2], bkh, accS[n], 0, 0, 0);
        accS[n] = __builtin_amdgcn_mfma_f32_16x16x32_bf16(aqh[s2], bkl, accS[n], 0, 0, 0);
      }
    }
    float corr[4];
    float pv_[4][4];
    #pragma unroll
    for (int r = 0; r < 4; r++) {
      float tm = fmaxf(fmaxf(accS[0][r], accS[1][r]), fmaxf(accS[2][r], accS[3][r]));
      tm = fmaxf(tm, __shfl_xor(tm, 1));
      tm = fmaxf(tm, __shfl_xor(tm, 2));
      tm = fmaxf(tm, __shfl_xor(tm, 4));
      tm = fmaxf(tm, __shfl_xor(tm, 8));
      const float mnew = fmaxf(mrun[r], tm);
      corr[r] = __expf(mrun[r] - mnew);
      mrun[r] = mnew;
      float ssum = 0.f;
      #pragma unroll
      for (int n = 0; n < 4; n++) {
        const float p = __expf(accS[n][r] - mnew);
        pv_[n][r] = p; ssum += p;
      }
      ssum += __shfl_xor(ssum, 1);
      ssum += __shfl_xor(ssum, 2);
      ssum += __shfl_xor(ssum, 4);
      ssum += __shfl_xor(ssum, 8);
      lrun[r] = lrun[r] * corr[r] + ssum;
    }
    #pragma unroll
    for (int n = 0; n < 4; n++)
      #pragma unroll
      for (int r = 0; r < 4; r++) accO[n][r] *= corr[r];
    #pragma unroll
    for (int n = 0; n < 4; n++)
      #pragma unroll
      for (int r = 0; r < 4; r++) {
        const float p = pv_[n][r];
        const unsigned short hi = f2bf(p);
        unsigned short* pp = &sP[(w * 16 + g * 4 + r) * LDW + (n * 16 + l15)];
        pp[0] = hi;
        pp[64] = f2bf(p - bf2f(hi));
      }
    #pragma unroll
    for (int s2 = 0; s2 < 2; s2++) {
      const short8 aph = *(const short8*)&sP[(w * 16 + l15) * LDW + s2 * 32 + g * 8];
      const short8 apl = *(const short8*)&sP[(w * 16 + l15) * LDW + 64 + s2 * 32 + g * 8];
      #pragma unroll
      for (int n = 0; n < 4; n++) {
        const short8 bvh = *(const short8*)&sVt[(n * 16 + l15) * LDW + s2 * 32 + g * 8];
        const short8 bvl = *(const short8*)&sVt[(n * 16 + l15) * LDW + 64 + s2 * 32 + g * 8];
        accO[n] = __builtin_amdgcn_mfma_f32_16x16x32_bf16(aph, bvh, accO[n], 0, 0, 0);
        accO[n] = __builtin_amdgcn_mfma_f32_16x16x32_bf16(apl, bvh, accO[n], 0, 0, 0);
        accO[n] = __builtin_amdgcn_mfma_f32_16x16x32_bf16(aph, bvl, accO[n], 0, 0, 0);
      }
    }
    __syncthreads();
    if (kt < S_ / 64 - 1) {
      __align__(16) unsigned short thi[8], tlo[8];
      #pragma unroll
      for (int j = 0; j < 8; j++) {
        const unsigned short hi = f2bf(krg[j]);
        thi[j] = hi; tlo[j] = f2bf(krg[j] - bf2f(hi));
      }
      *(uint4*)&sK[krow * LDW + dk0] = *(const uint4*)thi;
      *(uint4*)&sK[krow * LDW + 64 + dk0] = *(const uint4*)tlo;
      #pragma unroll
      for (int j = 0; j < 8; j++) {
        const unsigned short hi = f2bf(vrg[j]);
        thi[j] = hi; tlo[j] = f2bf(vrg[j] - bf2f(hi));
      }
      *(uint4*)&sVt[vd * LDW + vk0] = *(const uint4*)thi;
      *(uint4*)&sVt[vd * LDW + 64 + vk0] = *(const uint4*)tlo;
    }
    __syncthreads();
  }
  float inv[4];
  #pragma unroll
  for (int r = 0; r < 4; r++) inv[r] = 1.f / lrun[r];
  unsigned short* aoh = aos + ((size_t)((b << 10) + (chunk << 7) + w * 16)) * H_ + h * 64;
  #pragma unroll
  for (int n = 0; n < 4; n++)
    #pragma unroll
    for (int r = 0; r < 4; r++) {
      const float val = accO[n][r] * inv[r];
      const unsigned short hi = f2bf(val);
      const size_t idx = (size_t)(g * 4 + r) * H_ + n * 16 + l15;
      aoh[idx] = hi;
      aoh[APL + idx] = f2bf(val - bf2f(hi));
    }
}

// ------------------------- Wo GEMM: planar A (aos), planar W, fp32 out + resid
__global__ __launch_bounds__(256, 3) void gemm_wo(const unsigned short* __restrict__ As,
                                                  const unsigned short* __restrict__ Ws,
                                                  float* __restrict__ C,
                                                  const float* __restrict__ resid) {
  constexpr int K = 1024;
  constexpr int LDA = 40;
  __shared__ __align__(16) unsigned short sAh[128 * LDA];
  __shared__ __align__(16) unsigned short sAl[128 * LDA];
  __shared__ __align__(16) unsigned short sWh[128 * LDA];
  __shared__ __align__(16) unsigned short sWl[128 * LDA];
  const int tid = threadIdx.x;
  const int m0 = blockIdx.x << 7, n0 = blockIdx.y << 7;
  const int wave = tid >> 6, lane = tid & 63, wm = wave >> 1, wn = wave & 1;
  const int g16 = lane >> 4, l15 = lane & 15;
  const int row = tid >> 1, kq = (tid & 1) << 4;
  const unsigned short* pah = As + (size_t)(m0 + row) * K + kq;
  const unsigned short* pal = pah + APL;
  const unsigned short* pwh = Ws + (size_t)(n0 + row) * K + kq;
  const unsigned short* pwl = pwh + WPL;
  f32x4 acc[4][4];
  #pragma unroll
  for (int m = 0; m < 4; m++)
    #pragma unroll
    for (int n = 0; n < 4; n++) acc[m][n] = (f32x4){0.f, 0.f, 0.f, 0.f};

  uint4 rah0 = *(const uint4*)pah, rah1 = *(const uint4*)(pah + 8);
  uint4 ral0 = *(const uint4*)pal, ral1 = *(const uint4*)(pal + 8);
  uint4 rwh0 = *(const uint4*)pwh, rwh1 = *(const uint4*)(pwh + 8);
  uint4 rwl0 = *(const uint4*)pwl, rwl1 = *(const uint4*)(pwl + 8);

  for (int k0 = 0; k0 < K; k0 += 32) {
    __syncthreads();
    *(uint4*)&sAh[row * LDA + kq] = rah0;
    *(uint4*)&sAh[row * LDA + kq + 8] = rah1;
    *(uint4*)&sAl[row * LDA + kq] = ral0;
    *(uint4*)&sAl[row * LDA + kq + 8] = ral1;
    *(uint4*)&sWh[row * LDA + kq] = rwh0;
    *(uint4*)&sWh[row * LDA + kq + 8] = rwh1;
    *(uint4*)&sWl[row * LDA + kq] = rwl0;
    *(uint4*)&sWl[row * LDA + kq + 8] = rwl1;
    if (k0 + 32 < K) {
      rah0 = *(const uint4*)(pah + k0 + 32); rah1 = *(const uint4*)(pah + k0 + 40);
      ral0 = *(const uint4*)(pal + k0 + 32); ral1 = *(const uint4*)(pal + k0 + 40);
      rwh0 = *(const uint4*)(pwh + k0 + 32); rwh1 = *(const uint4*)(pwh + k0 + 40);
      rwl0 = *(const uint4*)(pwl + k0 + 32); rwl1 = *(const uint4*)(pwl + k0 + 40);
    }
    __syncthreads();
    short8 ah[4], al[4], wh[4], wl[4];
    #pragma unroll
    for (int m = 0; m < 4; m++) {
      ah[m] = *(const short8*)&sAh[(wm * 64 + m * 16 + l15) * LDA + g16 * 8];
      al[m] = *(const short8*)&sAl[(wm * 64 + m * 16 + l15) * LDA + g16 * 8];
    }
    #pragma unroll
    for (int n = 0; n < 4; n++) {
      wh[n] = *(const short8*)&sWh[(wn * 64 + n * 16 + l15) * LDA + g16 * 8];
      wl[n] = *(const short8*)&sWl[(wn * 64 + n * 16 + l15) * LDA + g16 * 8];
    }
    #pragma unroll
    for (int m = 0; m < 4; m++)
      #pragma unroll
      for (int n = 0; n < 4; n++) {
        acc[m][n] = __builtin_amdgcn_mfma_f32_16x16x32_bf16(ah[m], wh[n], acc[m][n], 0, 0, 0);
        acc[m][n] = __builtin_amdgcn_mfma_f32_16x16x32_bf16(al[m], wh[n], acc[m][n], 0, 0, 0);
        acc[m][n] = __builtin_amdgcn_mfma_f32_16x16x32_bf16(ah[m], wl[n], acc[m][n], 0, 0, 0);
      }
  }
  #pragma unroll
  for (int m = 0; m < 4; m++)
    #pragma unroll
    for (int r = 0; r < 4; r++) {
      const int grow = m0 + wm * 64 + m * 16 + g16 * 4 + r;
      #pragma unroll
      for (int n = 0; n < 4; n++) {
        const int gcol = n0 + wn * 64 + n * 16 + l15;
        C[(size_t)grow * 1024 + gcol] = acc[m][n][r] + resid[(size_t)grow * 1024 + gcol];
      }
    }
}

// ---------------------------------------------------------------- router
__global__ __launch_bounds__(256) void router_kernel(const float* __restrict__ x2,
                                                     const float* __restrict__ Wr,
                                                     float* __restrict__ probs,
                                                     int* __restrict__ texp,
                                                     float* __restrict__ tw) {
  const int wid = threadIdx.x >> 6, lane = threadIdx.x & 63;
  const int t = (blockIdx.x << 2) + wid;
  const float* xr = x2 + (size_t)t * H_;
  float4 xv[4];
  #pragma unroll
  for (int i = 0; i < 4; i++) xv[i] = *(const float4*)&xr[(i << 8) + (lane << 2)];
  float acc[E_];
  #pragma unroll
  for (int e = 0; e < E_; e++) acc[e] = 0.f;
  #pragma unroll
  for (int i = 0; i < 4; i++) {
    #pragma unroll
    for (int e = 0; e < E_; e++) {
      const float4 wv = *(const float4*)&Wr[e * H_ + (i << 8) + (lane << 2)];
      acc[e] += xv[i].x * wv.x + xv[i].y * wv.y + xv[i].z * wv.z + xv[i].w * wv.w;
    }
  }
  #pragma unroll
  for (int e = 0; e < E_; e++) {
    #pragma unroll
    for (int off = 32; off; off >>= 1) acc[e] += __shfl_xor(acc[e], off);
  }
  if (lane == 0) {
    float mx = acc[0];
    #pragma unroll
    for (int e = 1; e < E_; e++) mx = fmaxf(mx, acc[e]);
    float pp[E_]; float sum = 0.f;
    #pragma unroll
    for (int e = 0; e < E_; e++) { pp[e] = __expf(acc[e] - mx); sum += pp[e]; }
    const float isum = 1.f / sum;
    #pragma unroll
    for (int e = 0; e < E_; e++) pp[e] *= isum;
    float4 p0 = {pp[0], pp[1], pp[2], pp[3]};
    float4 p1 = {pp[4], pp[5], pp[6], pp[7]};
    *(float4*)&probs[(size_t)t * E_] = p0;
    *(float4*)&probs[(size_t)t * E_ + 4] = p1;
    int e0 = 0; float b0 = pp[0];
    #pragma unroll
    for (int e = 1; e < E_; e++) if (pp[e] > b0) { b0 = pp[e]; e0 = e; }
    int e1 = -1; float b1 = -1.f;
    #pragma unroll
    for (int e = 0; e < E_; e++) if (e != e0 && pp[e] > b1) { b1 = pp[e]; e1 = e; }
    const float iw = 1.f / (b0 + b1);
    texp[2 * t] = e0; texp[2 * t + 1] = e1;
    tw[2 * t] = b0 * iw; tw[2 * t + 1] = b1 * iw;
  }
}

__global__ __launch_bounds__(256) void fill_slots(int* slot_tok, float* slot_w) {
  const int i = blockIdx.x * 256 + threadIdx.x;
  if (i < PADSLOTS) { slot_tok[i] = -1; slot_w[i] = 0.f; }
}

// ------------------------------------------- finalize: reduce + build + scatter
__global__ __launch_bounds__(256) void finalize_kernel(const float* __restrict__ probs,
                                                       const int* __restrict__ texp,
                                                       const float* __restrict__ tw,
                                                       int* __restrict__ ntiles,
                                                       int* __restrict__ tile_expert,
                                                       int* __restrict__ slot_tok,
                                                       float* __restrict__ slot_w,
                                                       float* __restrict__ lb_out) {
  const int tid = threadIdx.x;
  const int w = tid >> 6, lane = tid & 63;
  __shared__ float sRed[4][E_];
  __shared__ int sCnt[4][E_];
  __shared__ int sPoff[E_];
  __shared__ int sBase[E_];
  __shared__ int sWcnt[4][E_];

  float ps[E_];
  #pragma unroll
  for (int e = 0; e < E_; e++) ps[e] = 0.f;
  #pragma unroll
  for (int i = 0; i < T_ / 256; i++) {
    const float4* pr = (const float4*)&probs[(size_t)(i * 256 + tid) * E_];
    const float4 a = pr[0], b = pr[1];
    ps[0] += a.x; ps[1] += a.y; ps[2] += a.z; ps[3] += a.w;
    ps[4] += b.x; ps[5] += b.y; ps[6] += b.z; ps[7] += b.w;
  }
  #pragma unroll
  for (int e = 0; e < E_; e++) {
    #pragma unroll
    for (int off = 32; off; off >>= 1) ps[e] += __shfl_xor(ps[e], off);
  }
  int cnt[E_];
  #pragma unroll
  for (int e = 0; e < E_; e++) cnt[e] = 0;
  #pragma unroll
  for (int i = 0; i < 2 * T_ / 256; i++) {
    const int ee = texp[i * 256 + tid];
    #pragma unroll
    for (int e = 0; e < E_; e++) cnt[e] += (ee == e) ? 1 : 0;
  }
  #pragma unroll
  for (int e = 0; e < E_; e++) {
    #pragma unroll
    for (int off = 32; off; off >>= 1) cnt[e] += __shfl_xor(cnt[e], off);
  }
  if (lane == 0) {
    #pragma unroll
    for (int e = 0; e < E_; e++) { sRed[w][e] = ps[e]; sCnt[w][e] = cnt[e]; }
  }
  __syncthreads();
  if (tid == 0) {
    int off = 0, tc = 0;
    float lb = 0.f;
    for (int e = 0; e < E_; e++) {
      const int c = sCnt[0][e] + sCnt[1][e] + sCnt[2][e] + sCnt[3][e];
      const float p = sRed[0][e] + sRed[1][e] + sRed[2][e] + sRed[3][e];
      sPoff[e] = off;
      const int nt = (c + 127) >> 7;
      for (int i = 0; i < nt; i++) tile_expert[tc++] = e;
      off += nt << 7;
      lb += ((float)c / (float)T_) * (p / (float)T_);
    }
    *ntiles = tc;
    lb_out[0] = lb * (float)E_;
  }
  if (tid < E_) sBase[tid] = 0;
  __syncthreads();
  for (int c = 0; c < 2 * T_ / 256; c++) {
    const int i = c * 256 + tid;
    const int e = texp[i];
    const float wv = tw[i];
    int myrank = 0;
    #pragma unroll
    for (int ee = 0; ee < E_; ee++) {
      const unsigned long long m = __ballot(e == ee);
      if (lane == 0) sWcnt[w][ee] = (int)__popcll(m);
      if (e == ee) myrank = (int)__popcll(m & ((1ull << lane) - 1ull));
    }
    __syncthreads();
    int pre = 0;
    #pragma unroll
    for (int w2 = 0; w2 < 4; w2++) if (w2 < w) pre += sWcnt[w2][e];
    const int slot = sPoff[e] + sBase[e] + pre + myrank;
    slot_tok[slot] = i >> 1;
    slot_w[slot] = wv;
    __syncthreads();
    if (tid < E_) sBase[tid] += sWcnt[0][tid] + sWcnt[1][tid] + sWcnt[2][tid] + sWcnt[3][tid];
    __syncthreads();
  }
}

// --------------------------- MoE GEMM1 (MFMA): h = silu(x@Wg^T)*(x@Wu^T)
// fp32 weights read DIRECTLY; in-loop f2bf staging; bounds (256,2).
// XCD-aligned flat grid: bid = tile*64 + n0idx -> XCD = n0idx%8 (L2 weight reuse).
// BK=64, LDA=72. Prefetch issued BEFORE barrier2.
__global__ __launch_bounds__(256, 2) void moe_gemm1(const unsigned short* __restrict__ x2b,
                                                    const float* __restrict__ Wg,
                                                    const float* __restrict__ Wu,
                                                    const int* __restrict__ slot_tok,
                                                    const int* __restrict__ tile_expert,
                                                    const int* __restrict__ ntiles,
                                                    unsigned short* __restrict__ hbuf) {
  const int bid = blockIdx.x;
  const int tile = bid >> 6;
  const int n0 = (bid & 63) << 6;
  if (tile >= *ntiles) return;
  constexpr int K = 1024;
  constexpr int LDA = 72;
  __shared__ __align__(16) unsigned short sA[128 * LDA];
  __shared__ __align__(16) unsigned short sG[64 * LDA];
  __shared__ __align__(16) unsigned short sU[64 * LDA];
  __shared__ int stok[128];
  const int tid = threadIdx.x;
  if (tid < 128) stok[tid] = slot_tok[tile * 128 + tid];
  __syncthreads();
  const int e = tile_expert[tile];
  const int wave = tid >> 6, lane = tid & 63, wm = wave >> 1, wn = wave & 1;
  const int g16 = lane >> 4, l15 = lane & 15;
  const int arow = tid >> 2, akq = (tid & 3) << 4;
  const int grow = tid >> 2, gkq = (tid & 3) << 3;
  int tok0 = stok[arow];       if (tok0 < 0) tok0 = 0;
  int tok1 = stok[64 + arow];  if (tok1 < 0) tok1 = 0;
  const unsigned short* a0 = x2b + (size_t)tok0 * K + akq;
  const unsigned short* a1 = x2b + (size_t)tok1 * K + akq;
  const float* gp = Wg + ((size_t)e * FF_ + n0 + grow) * K + gkq;
  const float* up = Wu + ((size_t)e * FF_ + n0 + grow) * K + gkq;

  f32x4 ag[4][2], au[4][2];
  #pragma unroll
  for (int m = 0; m < 4; m++)
    #pragma unroll
    for (int n = 0; n < 2; n++) { ag[m][n] = (f32x4){0,0,0,0}; au[m][n] = (f32x4){0,0,0,0}; }

  uint4 ra0 = *(const uint4*)a0, ra1 = *(const uint4*)(a0 + 8);
  uint4 ra2 = *(const uint4*)a1, ra3 = *(const uint4*)(a1 + 8);
  float4 rg[4], ru[4];
  rg[0] = *(const float4*)gp;        rg[1] = *(const float4*)(gp + 4);
  rg[2] = *(const float4*)(gp + 32); rg[3] = *(const float4*)(gp + 36);
  ru[0] = *(const float4*)up;        ru[1] = *(const float4*)(up + 4);
  ru[2] = *(const float4*)(up + 32); ru[3] = *(const float4*)(up + 36);

  for (int k0 = 0; k0 < K; k0 += 64) {
    __align__(16) unsigned short tg[16], tu[16];
    cvt8(rg[0], rg[1], tg); cvt8(rg[2], rg[3], tg + 8);
    cvt8(ru[0], ru[1], tu); cvt8(ru[2], ru[3], tu + 8);
    __syncthreads();
    *(uint4*)&sA[arow * LDA + akq] = ra0;
    *(uint4*)&sA[arow * LDA + akq + 8] = ra1;
    *(uint4*)&sA[(arow + 64) * LDA + akq] = ra2;
    *(uint4*)&sA[(arow + 64) * LDA + akq + 8] = ra3;
    *(uint4*)&sG[grow * LDA + gkq] = ((const uint4*)tg)[0];
    *(uint4*)&sG[grow * LDA + gkq + 32] = ((const uint4*)tg)[1];
    *(uint4*)&sU[grow * LDA + gkq] = ((const uint4*)tu)[0];
    *(uint4*)&sU[grow * LDA + gkq + 32] = ((const uint4*)tu)[1];
    // prefetch next phase BEFORE barrier2
    if (k0 + 64 < K) {
      ra0 = *(const uint4*)(a0 + k0 + 64); ra1 = *(const uint4*)(a0 + k0 + 72);
      ra2 = *(const uint4*)(a1 + k0 + 64); ra3 = *(const uint4*)(a1 + k0 + 72);
      rg[0] = *(const float4*)(gp + k0 + 64); rg[1] = *(const float4*)(gp + k0 + 68);
      rg[2] = *(const float4*)(gp + k0 + 96); rg[3] = *(const float4*)(gp + k0 + 100);
      ru[0] = *(const float4*)(up + k0 + 64); ru[1] = *(const float4*)(up + k0 + 68);
      ru[2] = *(const float4*)(up + k0 + 96); ru[3] = *(const float4*)(up + k0 + 100);
    }
    __syncthreads();
    #pragma unroll
    for (int ks = 0; ks < 2; ks++) {
      const int ko = ks * 32 + g16 * 8;
      short8 af[4], gf[2], uf[2];
      #pragma unroll
      for (int m = 0; m < 4; m++)
        af[m] = *(const short8*)&sA[(wm * 64 + m * 16 + l15) * LDA + ko];
      #pragma unroll
      for (int n = 0; n < 2; n++) {
        gf[n] = *(const short8*)&sG[(wn * 32 + n * 16 + l15) * LDA + ko];
        uf[n] = *(const short8*)&sU[(wn * 32 + n * 16 + l15) * LDA + ko];
      }
      #pragma unroll
      for (int m = 0; m < 4; m++)
        #pragma unroll
        for (int n = 0; n < 2; n++) {
          ag[m][n] = __builtin_amdgcn_mfma_f32_16x16x32_bf16(af[m], gf[n], ag[m][n], 0, 0, 0);
          au[m][n] = __builtin_amdgcn_mfma_f32_16x16x32_bf16(af[m], uf[n], au[m][n], 0, 0, 0);
        }
    }
  }
  #pragma unroll
  for (int m = 0; m < 4; m++)
    #pragma unroll
    for (int r = 0; r < 4; r++) {
      const int slotloc = wm * 64 + m * 16 + g16 * 4 + r;
      unsigned short* hr = hbuf + (size_t)(tile * 128 + slotloc) * FF_ + n0;
      #pragma unroll
      for (int n = 0; n < 2; n++) {
        const int col = wn * 32 + n * 16 + l15;
        const float g = ag[m][n][r], u = au[m][n][r];
        const float hv = (g / (1.f + __expf(-g))) * u;
        hr[col] = f2bf(hv);
      }
    }
}

// --------------------------- MoE GEMM2 (MFMA): out += w * (h @ Wd^T)
// bf16 mirror Wdb, BK=64, LDA=72. hbuf-coherent flat grid; bounds (256,2).
// Prefetch issued BEFORE barrier2.
__global__ __launch_bounds__(256, 2) void moe_gemm2(const unsigned short* __restrict__ hbuf,
                                                    const unsigned short* __restrict__ Wdb,
                                                    const int* __restrict__ slot_tok,
                                                    const float* __restrict__ slot_w,
                                                    const int* __restrict__ tile_expert,
                                                    const int* __restrict__ ntiles,
                                                    float* __restrict__ out) {
  const int bid = blockIdx.x;
  const int tile = bid % MAXTILES;
  const int n0 = (bid / MAXTILES) << 7;
  if (tile >= *ntiles) return;
  constexpr int K = 4096;
  constexpr int LDA = 72;
  __shared__ __align__(16) unsigned short sA[128 * LDA];
  __shared__ __align__(16) unsigned short sB[128 * LDA];
  __shared__ int s_tok[128];
  __shared__ float s_w[128];
  const int tid = threadIdx.x;
  if (tid < 128) { s_tok[tid] = slot_tok[tile * 128 + tid]; s_w[tid] = slot_w[tile * 128 + tid]; }
  const int e = tile_expert[tile];
  const int wave = tid >> 6, lane = tid & 63, wm = wave >> 1, wn = wave & 1;
  const int g16 = lane >> 4, l15 = lane & 15;
  const int arow = tid >> 1, akq = (tid & 1) << 4;
  const unsigned short* ap = hbuf + (size_t)(tile * 128 + arow) * K + akq;
  const unsigned short* wp = Wdb + ((size_t)e * H_ + n0 + arow) * K + akq;

  f32x4 acc[4][4];
  #pragma unroll
  for (int m = 0; m < 4; m++)
    #pragma unroll
    for (int n = 0; n < 4; n++) acc[m][n] = (f32x4){0,0,0,0};

  uint4 ra0 = *(const uint4*)ap, ra1 = *(const uint4*)(ap + 8);
  uint4 ra2 = *(const uint4*)(ap + 32), ra3 = *(const uint4*)(ap + 40);
  uint4 rb0 = *(const uint4*)wp, rb1 = *(const uint4*)(wp + 8);
  uint4 rb2 = *(const uint4*)(wp + 32), rb3 = *(const uint4*)(wp + 40);

  for (int k0 = 0; k0 < K; k0 += 64) {
    __syncthreads();
    *(uint4*)&sA[arow * LDA + akq] = ra0;
    *(uint4*)&sA[arow * LDA + akq + 8] = ra1;
    *(uint4*)&sA[arow * LDA + akq + 32] = ra2;
    *(uint4*)&sA[arow * LDA + akq + 40] = ra3;
    *(uint4*)&sB[arow * LDA + akq] = rb0;
    *(uint4*)&sB[arow * LDA + akq + 8] = rb1;
    *(uint4*)&sB[arow * LDA + akq + 32] = rb2;
    *(uint4*)&sB[arow * LDA + akq + 40] = rb3;
    // prefetch next phase BEFORE barrier2
    if (k0 + 64 < K) {
      ra0 = *(const uint4*)(ap + k0 + 64); ra1 = *(const uint4*)(ap + k0 + 72);
      ra2 = *(const uint4*)(ap + k0 + 96); ra3 = *(const uint4*)(ap + k0 + 104);
      rb0 = *(const uint4*)(wp + k0 + 64); rb1 = *(const uint4*)(wp + k0 + 72);
      rb2 = *(const uint4*)(wp + k0 + 96); rb3 = *(const uint4*)(wp + k0 + 104);
    }
    __syncthreads();
    #pragma unroll
    for (int ks = 0; ks < 2; ks++) {
      const int ko = ks * 32 + g16 * 8;
      short8 af[4], bf_[4];
      #pragma unroll
      for (int m = 0; m < 4; m++)
        af[m] = *(const short8*)&sA[(wm * 64 + m * 16 + l15) * LDA + ko];
      #pragma unroll
      for (int n = 0; n < 4; n++)
        bf_[n] = *(const short8*)&sB[(wn * 64 + n * 16 + l15) * LDA + ko];
      #pragma unroll
      for (int m = 0; m < 4; m++)
        #pragma unroll
        for (int n = 0; n < 4; n++)
          acc[m][n] = __builtin_amdgcn_mfma_f32_16x16x32_bf16(af[m], bf_[n], acc[m][n], 0, 0, 0);
    }
  }
  #pragma unroll
  for (int m = 0; m < 4; m++)
    #pragma unroll
    for (int r = 0; r < 4; r++) {
      const int slotloc = wm * 64 + m * 16 + g16 * 4 + r;
      const int tok = s_tok[slotloc];
      if (tok < 0) continue;
      const float wv = s_w[slotloc];
      float* orow = out + (size_t)tok * H_ + n0;
      #pragma unroll
      for (int n = 0; n < 4; n++) {
        const int col = wn * 64 + n * 16 + l15;
        atomicAdd(&orow[col], wv * acc[m][n][r]);
      }
    }
}

}  // namespace

extern "C" void kernel_launch(void* const* d_in, const int* in_sizes, int n_in,
                              void* d_out, int out_size, void* d_ws, size_t ws_size,
                              hipStream_t stream) {
  const float* hs  = (const float*)d_in[0];
  const float* ln1 = (const float*)d_in[2];
  const float* ln2 = (const float*)d_in[3];
  const float* Wq  = (const float*)d_in[4];
  const float* Wk  = (const float*)d_in[5];
  const float* Wv  = (const float*)d_in[6];
  const float* Wo  = (const float*)d_in[7];
  const float* Wr  = (const float*)d_in[8];
  const float* Wg  = (const float*)d_in[9];
  const float* Wu  = (const float*)d_in[10];
  const float* Wd  = (const float*)d_in[11];
  float* out = (float*)d_out;
  char* ws = (char*)d_ws;

  constexpr size_t MB = (size_t)1 << 20;
  unsigned short* x1s = (unsigned short*)(ws);             // 8 MiB (hi+lo planes)
  float* qb  = (float*)(ws + 8 * MB);                      // 8 MiB
  float* kb  = (float*)(ws + 16 * MB);
  float* vb  = (float*)(ws + 24 * MB);
  unsigned short* aos = (unsigned short*)(ws + 32 * MB);   // 8 MiB (hi+lo planes)
  float* x2  = (float*)(ws + 40 * MB);                     // 8 MiB
  unsigned short* x2b  = (unsigned short*)(ws + 48 * MB);  // 4 MiB
  unsigned short* hbuf = (unsigned short*)(ws + 52 * MB);  // 40 MiB
  // QKV/O weight splits live INSIDE hbuf region (dead before moe_gemm1 writes)
  unsigned short* wqs = (unsigned short*)(ws + 52 * MB);   // 4 MiB each
  unsigned short* wks = (unsigned short*)(ws + 56 * MB);
  unsigned short* wvs = (unsigned short*)(ws + 60 * MB);
  unsigned short* wos = (unsigned short*)(ws + 64 * MB);
  char* meta = ws + 92 * MB;
  int*   ntl     = (int*)(meta + 256);
  int*   texpert = (int*)(meta + 512);
  int*   texp    = (int*)(meta + 1024);
  float* tw      = (float*)(meta + 1024 + 16384);
  int*   stok    = (int*)(meta + 1024 + 32768);
  float* sw      = (float*)(meta + 1024 + 32768 + (size_t)PADSLOTS * 4);
  float* probs   = (float*)(meta + 1024 + 32768 + (size_t)PADSLOTS * 8);
  constexpr size_t WELEMS = (size_t)E_ * FF_ * H_;   // 33,554,432
  unsigned short* wdb = (unsigned short*)(ws + 96 * MB);   // 64 MiB Wd bf16 mirror

  // split QKV/O weights (one-time per call; L2-sized, ~6 us)
  const int wblk = (int)(WPL / 8 / 256);   // 512
  cvt_wsplit<<<dim3(wblk), 256, 0, stream>>>(Wq, wqs, (int)(WPL / 8));
  cvt_wsplit<<<dim3(wblk), 256, 0, stream>>>(Wk, wks, (int)(WPL / 8));
  cvt_wsplit<<<dim3(wblk), 256, 0, stream>>>(Wv, wvs, (int)(WPL / 8));
  cvt_wsplit<<<dim3(wblk), 256, 0, stream>>>(Wo, wos, (int)(WPL / 8));

  rmsnorm_kernel<2><<<dim3(T_), dim3(256), 0, stream>>>(hs, ln1, nullptr, x1s);

  gemm_split<0><<<dim3(16, 8, 3), 256, 0, stream>>>(x1s, wqs, wks, wvs, qb, kb, vb, nullptr);

  const int rope_blocks = (T_ * NH_ * 32) / 256;
  rope_kernel<<<dim3(rope_blocks), 256, 0, stream>>>(qb);
  rope_kernel<<<dim3(rope_blocks), 256, 0, stream>>>(kb);

  attn_mfma<<<dim3(B_ * NH_ * (S_ / 128)), 512, 0, stream>>>(qb, kb, vb, aos);

  gemm_wo<<<dim3(16, 8), 256, 0, stream>>>(aos, wos, out, hs);

  rmsnorm_kernel<1><<<dim3(T_), dim3(256), 0, stream>>>(out, ln2, x2, x2b);
  router_kernel<<<dim3(T_ / 4), 256, 0, stream>>>(x2, Wr, probs, texp, tw);
  fill_slots<<<dim3(PADSLOTS / 256), 256, 0, stream>>>(stok, sw);
  finalize_kernel<<<dim3(1), dim3(256), 0, stream>>>(probs, texp, tw, ntl, texpert,
                                                     stok, sw, out + (size_t)T_ * H_);

  moe_gemm1<<<dim3(MAXTILES * (FF_ / 64)), 256, 0, stream>>>(x2b, Wg, Wu, stok, texpert, ntl, hbuf);

  // Wd bf16 mirror right before gemm2 (leaves wdb L3-hot)
  const int cvt_blocks = (int)(WELEMS / 8 / 256);   // 16384
  cvt_ws<<<dim3(cvt_blocks), 256, 0, stream>>>(Wd, wdb, (int)(WELEMS / 8));

  moe_gemm2<<<dim3(MAXTILES * (H_ / 128)), 256, 0, stream>>>(hbuf, wdb, stok, sw, texpert, ntl, out);
}